// Round 5
// baseline (493651.953 us; speedup 1.0000x reference)
//
#include <hip/hip_runtime.h>
#include <hip/hip_cooperative_groups.h>
#include <cmath>

namespace cg = cooperative_groups;

// Problem dims (fixed): T=4096, I=512, H=2048, F=256
#define NSTEP 8191   // 4096 enc + 4095 dec

// ---------------- small kernels ----------------
__global__ void fillK(float* p, int n, float v){
  for (int i = blockIdx.x*blockDim.x + threadIdx.x; i < n; i += gridDim.x*blockDim.x) p[i] = v;
}

__global__ void copyK(float* dst, const float* __restrict__ src, int n){
  int i = blockIdx.x*blockDim.x + threadIdx.x;
  if (i < n) dst[i] = src[i];
}

// coalesced 2-pass mean: mean[i] = sum_t seq[t,i] / (1e-6 + count_t(mask!=0))
__global__ void mean1K(const float* __restrict__ seq, const float* __restrict__ mask,
                       float* __restrict__ Sp, float* __restrict__ Cp){
  int bb = blockIdx.x, i = threadIdx.x;      // 64 blocks x 512 threads
  float s = 0.f, c = 0.f;
  for (int tt = 64*bb; tt < 64*bb + 64; ++tt){
    size_t o = (size_t)tt*512 + i;
    s += seq[o];
    c += (mask[o] != 0.f) ? 1.f : 0.f;
  }
  Sp[bb*512 + i] = s; Cp[bb*512 + i] = c;
}
__global__ void mean2K(const float* __restrict__ Sp, const float* __restrict__ Cp,
                       float* __restrict__ meanv){
  int i = threadIdx.x;                        // 1 block x 512
  float s = 0.f, c = 0.f;
  for (int bb = 0; bb < 64; ++bb){ s += Sp[bb*512 + i]; c += Cp[bb*512 + i]; }
  meanv[i] = s / (1e-6f + c);
}

// ---------------- parallel affine scan for prex/xh recurrence ----------------
__device__ __forceinline__ void scan_ac(const float* __restrict__ Gx,
                                        const float* __restrict__ mask,
                                        const float* __restrict__ seq,
                                        float mn, int r, int i, float& a, float& c){
  int src = (r < 4096) ? r : (8190 - r);
  size_t o = (size_t)src*512 + i;
  float g = Gx[o], m = mask[o], x = seq[o];
  a = (1.f - m)*g;
  c = m*x + (1.f - m)*(1.f - g)*mn;
}
__global__ void scanSegK(const float* __restrict__ Gx, const float* __restrict__ mask,
                         const float* __restrict__ seq, const float* __restrict__ meanv,
                         float* __restrict__ segA, float* __restrict__ segC){
  int bb = blockIdx.x, i = threadIdx.x;       // 64 blocks x 512 threads
  float mn = meanv[i];
  float A = 1.f, C = 0.f;
  int r1 = 128*bb + 128; if (r1 > NSTEP) r1 = NSTEP;
  for (int r = 128*bb; r < r1; ++r){
    float a, c; scan_ac(Gx, mask, seq, mn, r, i, a, c);
    A = a*A; C = a*C + c;
  }
  segA[bb*512 + i] = A; segC[bb*512 + i] = C;
}
__global__ void scanFixK(const float* __restrict__ segA, const float* __restrict__ segC,
                         const float* __restrict__ prex0, float* __restrict__ segX0){
  int i = threadIdx.x;                        // 1 block x 512
  float x = prex0[i];
  for (int bb = 0; bb < 64; ++bb){
    segX0[bb*512 + i] = x;
    x = segA[bb*512 + i]*x + segC[bb*512 + i];
  }
}
__global__ void scanEmitK(const float* __restrict__ Gx, const float* __restrict__ mask,
                          const float* __restrict__ seq, const float* __restrict__ meanv,
                          const float* __restrict__ segX0, float* __restrict__ xh){
  int bb = blockIdx.x, i = threadIdx.x;
  float mn = meanv[i];
  float x = segX0[bb*512 + i];
  int r1 = 128*bb + 128; if (r1 > NSTEP) r1 = NSTEP;
  for (int r = 128*bb; r < r1; ++r){
    float a, c; scan_ac(Gx, mask, seq, mn, r, i, a, c);
    x = a*x + c;
    xh[(size_t)r*512 + i] = x;
  }
}

// ---------------- generic fp32 GEMM: C = act(A@B + bias) [+ C if beta] ----------
#define BM 128
#define BN 128
#define BK 8
__launch_bounds__(256)
__global__ void gemmK(const float* __restrict__ A, const float* __restrict__ B,
                      float* __restrict__ C, int M, int N, int K,
                      const float* __restrict__ bias, int act, int beta, int amap,
                      int rowoff){
  __shared__ float As[BK][BM+4];
  __shared__ float Bs[BK][BN+4];
  int tid = threadIdx.x;
  int r0 = blockIdx.y * BM, c0 = blockIdx.x * BN;
  int tr = tid >> 4, tc = tid & 15;
  int ar = tid >> 1, ak = (tid & 1)*4;
  int bkr = tid >> 5, bkc = (tid & 31)*4;
  float acc[8][8] = {};

  for (int k0 = 0; k0 < K; k0 += BK){
    int r = r0 + ar;
    float4 av = make_float4(0.f,0.f,0.f,0.f);
    if (r < M){
      int g = rowoff + r;
      int rs = amap ? (g < 4096 ? g : 8190 - g) : r;
      av = *(const float4*)(A + (size_t)rs*K + k0 + ak);
    }
    As[ak+0][ar] = av.x; As[ak+1][ar] = av.y; As[ak+2][ar] = av.z; As[ak+3][ar] = av.w;
    *(float4*)(&Bs[bkr][bkc]) = *(const float4*)(B + (size_t)(k0 + bkr)*N + c0 + bkc);
    __syncthreads();
    #pragma unroll
    for (int kk = 0; kk < BK; ++kk){
      float a[8], bb[8];
      #pragma unroll
      for (int i = 0; i < 8; ++i) a[i]  = As[kk][tr*8 + i];
      #pragma unroll
      for (int j = 0; j < 8; ++j) bb[j] = Bs[kk][tc*8 + j];
      #pragma unroll
      for (int i = 0; i < 8; ++i)
        #pragma unroll
        for (int j = 0; j < 8; ++j)
          acc[i][j] += a[i]*bb[j];
    }
    __syncthreads();
  }

  #pragma unroll
  for (int i = 0; i < 8; ++i){
    int r = r0 + tr*8 + i;
    if (r >= M) continue;
    float v[8];
    #pragma unroll
    for (int j = 0; j < 8; ++j){
      int c = c0 + tc*8 + j;
      float x = acc[i][j];
      if (bias) x += bias[c];
      if (act == 1) x = expf(-fmaxf(x, 0.f));
      v[j] = x;
    }
    float* cp = C + (size_t)r*N + c0 + tc*8;
    if (beta){
      float4 o0 = *(const float4*)(cp);
      float4 o1 = *(const float4*)(cp + 4);
      v[0]+=o0.x; v[1]+=o0.y; v[2]+=o0.z; v[3]+=o0.w;
      v[4]+=o1.x; v[5]+=o1.y; v[6]+=o1.z; v[7]+=o1.w;
    }
    *(float4*)(cp)     = make_float4(v[0],v[1],v[2],v[3]);
    *(float4*)(cp + 4) = make_float4(v[4],v[5],v[6],v[7]);
  }
}

// ---------------- cooperative chunk kernel --------------------------------
// 256 WGs x 256 thr. WG w owns output cols [8w,8w+8); thread t owns k-slice
// [8t,8t+8). U register-resident (192 VGPR). 2 grid.sync()/step (+2 at MLP).
__launch_bounds__(256, 1)
__global__ void rnnCoopK(const float* __restrict__ U, const float* __restrict__ PreC,
                         int c0, int len,
                         const float* __restrict__ Gh, const float* __restrict__ dts,
                         const float* __restrict__ We, const float* __restrict__ be,
                         const float* __restrict__ Wd, const float* __restrict__ bd,
                         float* hbuf, float* rhdbuf, float* hpbuf, float* featbuf,
                         float* __restrict__ HpDec){
  cg::grid_group grid = cg::this_grid();
  const int w = blockIdx.x;
  const int t = threadIdx.x;
  const int lane = t & 63, wv = t >> 6;
  __shared__ float redA[4][8], redB[4][8], redH[4][8], ldsH[8], ldsHd[8];

  // register-resident U slices: uz/ur/uh[cc][i] = U[8t+i][{0,2048,4096}+8w+cc]
  float uz[8][8], ur[8][8], uh[8][8];
  #pragma unroll
  for (int i = 0; i < 8; ++i){
    const float* row = U + (size_t)(8*t + i)*6144 + 8*w;
    #pragma unroll
    for (int cc = 0; cc < 8; ++cc){
      uz[cc][i] = row[cc];
      ur[cc][i] = row[2048 + cc];
      uh[cc][i] = row[4096 + cc];
    }
  }

  // one-step-ahead prefetch (registers only)
  float ghn[8]; float pzn = 0.f, prn = 0.f, phn = 0.f, dtn = 0.f;
  auto prefetch = [&](int g){
    int src = (g < 4096) ? g : (8190 - g);
    const float* gr = Gh + (size_t)src*2048 + 8*t;
    #pragma unroll
    for (int i = 0; i < 8; ++i) ghn[i] = gr[i];
    const float* prow = PreC + (size_t)(g - c0)*6144;
    if (t < 8){ pzn = prow[8*w + t]; phn = prow[4096 + 8*w + t]; dtn = dts[src]; }
    else if (t < 16){ prn = prow[2048 + 8*w + (t - 8)]; }
  };
  prefetch(c0);

  for (int sl = 0; sl < len; ++sl){
    int g = c0 + sl;

    if (g == 4096){
      // ---- mid MLP: h = relu(relu(hp)@We + be) @ Wd + bd ----
      // hpbuf(step 4095) visible: written before last grid.sync of prev step.
      {
        float part = 0.f;
        #pragma unroll
        for (int i = 0; i < 8; ++i){
          float hp = fmaxf(hpbuf[8*t + i], 0.f);
          part += hp * We[(size_t)(8*t + i)*256 + w];
        }
        #pragma unroll
        for (int o = 32; o; o >>= 1) part += __shfl_down(part, o);
        if (lane == 0) redA[wv][0] = part;
        __syncthreads();
        if (t == 0)
          featbuf[w] = fmaxf(redA[0][0]+redA[1][0]+redA[2][0]+redA[3][0] + be[w], 0.f);
      }
      grid.sync();
      {
        float fv = featbuf[t];
        #pragma unroll
        for (int cc = 0; cc < 8; ++cc){
          float v = fv * Wd[(size_t)t*2048 + 8*w + cc];
          #pragma unroll
          for (int o = 32; o; o >>= 1) v += __shfl_down(v, o);
          if (lane == 0) redB[wv][cc] = v;
        }
        __syncthreads();
        if (t < 8)
          hbuf[8*w + t] = redB[0][t]+redB[1][t]+redB[2][t]+redB[3][t] + bd[8*w + t];
      }
      grid.sync();
    }

    // ---------- phase A: z,r = sigmoid(pre + (gh*h)@U1) ----------
    float ghc[8];
    #pragma unroll
    for (int i = 0; i < 8; ++i) ghc[i] = ghn[i];
    float pz = pzn, pr = prn, ph = phn, dtv = dtn;

    float hd[8];
    #pragma unroll
    for (int i = 0; i < 8; ++i){
      float hv = hbuf[8*t + i];                 // visible: synced at prev step end
      hd[i] = hv * ghc[i];
      if (t == w){ ldsH[i] = hv; ldsHd[i] = hd[i]; }
    }
    if (sl + 1 < len) prefetch(g + 1);

    float accz[8], accr[8];
    #pragma unroll
    for (int cc = 0; cc < 8; ++cc){
      float az = 0.f, ar_ = 0.f;
      #pragma unroll
      for (int i = 0; i < 8; ++i){ az += hd[i]*uz[cc][i]; ar_ += hd[i]*ur[cc][i]; }
      accz[cc] = az; accr[cc] = ar_;
    }
    #pragma unroll
    for (int cc = 0; cc < 8; ++cc){
      float v = accz[cc];
      #pragma unroll
      for (int o = 32; o; o >>= 1) v += __shfl_down(v, o);
      if (lane == 0) redA[wv][cc] = v;
      v = accr[cc];
      #pragma unroll
      for (int o = 32; o; o >>= 1) v += __shfl_down(v, o);
      if (lane == 0) redB[wv][cc] = v;
    }
    __syncthreads();
    float zreg = 0.f;
    if (t < 8){
      float s = redA[0][t]+redA[1][t]+redA[2][t]+redA[3][t] + pz;
      zreg = 1.f/(1.f + expf(-s));              // lives in register across grid.sync
    } else if (t < 16){
      int cc = t - 8;
      float s = redB[0][cc]+redB[1][cc]+redB[2][cc]+redB[3][cc] + pr;
      float r = 1.f/(1.f + expf(-s));
      rhdbuf[8*w + cc] = r * ldsHd[cc];
    }
    grid.sync();

    // ---------- phase B: htil = tanh(pre_h + (r*hd)@U2); h update ----------
    float rvv[8];
    #pragma unroll
    for (int i = 0; i < 8; ++i) rvv[i] = rhdbuf[8*t + i];
    float acch[8];
    #pragma unroll
    for (int cc = 0; cc < 8; ++cc){
      float a = 0.f;
      #pragma unroll
      for (int i = 0; i < 8; ++i) a += rvv[i]*uh[cc][i];
      acch[cc] = a;
    }
    #pragma unroll
    for (int cc = 0; cc < 8; ++cc){
      float v = acch[cc];
      #pragma unroll
      for (int o = 32; o; o >>= 1) v += __shfl_down(v, o);
      if (lane == 0) redH[wv][cc] = v;
    }
    __syncthreads();
    if (t < 8){
      float u    = redH[0][t]+redH[1][t]+redH[2][t]+redH[3][t] + ph;
      float htil = tanhf(u);
      float z = zreg, hdv = ldsHd[t], hold = ldsH[t];
      float hp = z*hdv + (1.f - z)*htil;
      float dh = (1.f - z)*(htil - hdv);
      hbuf[8*w + t]  = hold + dtv*dh;
      hpbuf[8*w + t] = hp;
      if (g >= 4096) HpDec[(size_t)(8190 - g)*2048 + 8*w + t] = hp;   // pre-reversed
    }
    grid.sync();
  }
}

// ---------------- fallback per-step kernels (no cross-WG sync; proven R4 path) ----
__launch_bounds__(256)
__global__ void stepAK(const float* __restrict__ U, const float* __restrict__ pre,
                       const float* __restrict__ ghrow, const float* __restrict__ hbuf,
                       float* __restrict__ zbuf, float* __restrict__ rhdbuf){
  __shared__ float hdl[2048];
  __shared__ float red[16][17];
  int w = blockIdx.x, t = threadIdx.x;
  for (int i = t; i < 2048; i += 256) hdl[i] = hbuf[i] * ghrow[i];
  __syncthreads();
  int jo = t & 15, ko = t >> 4;
  const float* Ucol = U + 16*w + jo;
  float s = 0.f;
  int k0 = ko*128;
  #pragma unroll 4
  for (int k = k0; k < k0 + 128; ++k) s += hdl[k] * Ucol[(size_t)k*6144];
  red[ko][jo] = s;
  __syncthreads();
  if (t < 16){
    float a = 0.f;
    #pragma unroll
    for (int q = 0; q < 16; ++q) a += red[q][t];
    int j = 16*w + t;
    float v = 1.f/(1.f + expf(-(pre[j] + a)));
    if (j < 2048) zbuf[j] = v;
    else          rhdbuf[j - 2048] = v * hdl[j - 2048];
  }
}

__launch_bounds__(256)
__global__ void stepBK(const float* __restrict__ U, const float* __restrict__ prh,
                       const float* __restrict__ ghrow, const float* __restrict__ dtp,
                       const float* __restrict__ zbuf, const float* __restrict__ rhdbuf,
                       float* __restrict__ hbuf, float* __restrict__ hpbuf,
                       float* __restrict__ hpdec){
  __shared__ float rl[2048];
  __shared__ float red[16][17];
  int w = blockIdx.x, t = threadIdx.x;
  for (int i = t; i < 2048; i += 256) rl[i] = rhdbuf[i];
  __syncthreads();
  int jo = t & 15, ko = t >> 4;
  const float* Ucol = U + 4096 + 16*w + jo;
  float s = 0.f;
  int k0 = ko*128;
  #pragma unroll 4
  for (int k = k0; k < k0 + 128; ++k) s += rl[k] * Ucol[(size_t)k*6144];
  red[ko][jo] = s;
  __syncthreads();
  if (t < 16){
    float a = 0.f;
    #pragma unroll
    for (int q = 0; q < 16; ++q) a += red[q][t];
    int j = 16*w + t;
    float htil = tanhf(prh[j] + a);
    float z    = zbuf[j];
    float hold = hbuf[j];
    float hd   = hold * ghrow[j];
    float hp   = z*hd + (1.f - z)*htil;
    float dh   = (1.f - z)*(htil - hd);
    hbuf[j]  = hold + dtp[0]*dh;
    hpbuf[j] = hp;
    if (hpdec) hpdec[j] = hp;
  }
}

__launch_bounds__(256)
__global__ void mlp1K(const float* __restrict__ hpbuf, const float* __restrict__ We,
                      const float* __restrict__ be, float* __restrict__ featbuf){
  __shared__ float red[16][17];
  int w = blockIdx.x, t = threadIdx.x;      // 16 WGs
  int fo = t & 15, ko = t >> 4;
  int f = 16*w + fo;
  float s = 0.f;
  int k0 = ko*128;
  for (int k = k0; k < k0 + 128; ++k)
    s += fmaxf(hpbuf[k], 0.f) * We[(size_t)k*256 + f];
  red[ko][fo] = s;
  __syncthreads();
  if (t < 16){
    float a = 0.f;
    #pragma unroll
    for (int q = 0; q < 16; ++q) a += red[q][t];
    featbuf[16*w + t] = fmaxf(a + be[16*w + t], 0.f);
  }
}
__launch_bounds__(256)
__global__ void mlp2K(const float* __restrict__ featbuf, const float* __restrict__ Wd,
                      const float* __restrict__ bd, float* __restrict__ hbuf){
  __shared__ float red[16][17];
  int w = blockIdx.x, t = threadIdx.x;      // 128 WGs
  int jo = t & 15, ko = t >> 4;
  int j = 16*w + jo;
  float s = 0.f;
  int k0 = ko*16;
  for (int k = k0; k < k0 + 16; ++k)
    s += featbuf[k] * Wd[(size_t)k*2048 + j];
  red[ko][jo] = s;
  __syncthreads();
  if (t < 16){
    float a = 0.f;
    #pragma unroll
    for (int q = 0; q < 16; ++q) a += red[q][t];
    hbuf[16*w + t] = a + bd[16*w + t];
  }
}

// ---------------- launch ----------------
extern "C" void kernel_launch(void* const* d_in, const int* in_sizes, int n_in,
                              void* d_out, int out_size, void* d_ws, size_t ws_size,
                              hipStream_t stream){
  (void)in_sizes; (void)n_in;
  const float* seq   = (const float*)d_in[0];
  const float* mask  = (const float*)d_in[1];
  const float* delta = (const float*)d_in[2];
  const float* dt    = (const float*)d_in[3];
  const float* h0    = (const float*)d_in[4];
  /* d_in[5] = dh0: carried dh never read by the reference cell */
  const float* prex0 = (const float*)d_in[6];
  const float* Wgx   = (const float*)d_in[7];
  const float* bgx   = (const float*)d_in[8];
  const float* Wgh   = (const float*)d_in[9];
  const float* bgh   = (const float*)d_in[10];
  const float* W     = (const float*)d_in[11];
  const float* U     = (const float*)d_in[12];
  const float* V     = (const float*)d_in[13];
  const float* b     = (const float*)d_in[14];
  const float* We    = (const float*)d_in[15];
  const float* be    = (const float*)d_in[16];
  const float* Wd    = (const float*)d_in[17];
  const float* bd    = (const float*)d_in[18];
  const float* Wo    = (const float*)d_in[19];
  const float* bo    = (const float*)d_in[20];

  float* wsf = (float*)d_ws;
  size_t wsFloats = ws_size / 4;
  size_t off = 0;
  float* meanv  = wsf + off;  off += 512;
  float* hbuf   = wsf + off;  off += 2048;
  float* zbuf   = wsf + off;  off += 2048;
  float* rhdbuf = wsf + off;  off += 2048;
  float* hpbuf  = wsf + off;  off += 2048;
  float* featbuf= wsf + off;  off += 256;
  float* Sp     = wsf + off;  off += (size_t)64*512;
  float* Cp     = wsf + off;  off += (size_t)64*512;
  float* Gh     = wsf + off;  off += (size_t)4096*2048;
  float* xh_all = wsf + off;  off += (size_t)NSTEP*512;
  float* HpDec  = wsf + off;  off += (size_t)4095*2048;
  size_t fixedF = off;

  // chunk area: overlays {Gx, scan temps} during precompute, PreTab chunk after
  float* area  = wsf + fixedF;
  float* Gx    = area;                                   // 4096*512
  float* segA  = area + (size_t)4096*512;                // 64*512
  float* segC  = segA + (size_t)64*512;
  float* segX0 = segC + (size_t)64*512;
  size_t preNeed = (size_t)4096*512 + (size_t)3*64*512;

  size_t areaF = (wsFloats > fixedF) ? (wsFloats - fixedF) : 0;
  long chunkSteps = (long)(areaF / 6144);
  if (areaF < preNeed || chunkSteps < 64){
    fillK<<<dim3(256), dim3(256), 0, stream>>>((float*)d_out, out_size,
                                               1.0e6f + (float)(ws_size >> 20));
    return;
  }
  if (chunkSteps > NSTEP) chunkSteps = NSTEP;
  int nch  = (int)((NSTEP + chunkSteps - 1) / chunkSteps);
  int clen = (NSTEP + nch - 1) / nch;

  // ---- precompute ----
  mean1K<<<dim3(64), dim3(512), 0, stream>>>(seq, mask, Sp, Cp);
  mean2K<<<dim3(1),  dim3(512), 0, stream>>>(Sp, Cp, meanv);
  gemmK<<<dim3(4, 32),  dim3(256), 0, stream>>>(delta, Wgx, Gx, 4096, 512, 512, bgx, 1, 0, 0, 0);
  gemmK<<<dim3(16, 32), dim3(256), 0, stream>>>(delta, Wgh, Gh, 4096, 2048, 512, bgh, 1, 0, 0, 0);
  scanSegK<<<dim3(64), dim3(512), 0, stream>>>(Gx, mask, seq, meanv, segA, segC);
  scanFixK<<<dim3(1),  dim3(512), 0, stream>>>(segA, segC, prex0, segX0);
  scanEmitK<<<dim3(64), dim3(512), 0, stream>>>(Gx, mask, seq, meanv, segX0, xh_all);
  copyK<<<dim3(8), dim3(256), 0, stream>>>(hbuf, h0, 2048);

  // ---- chunked recurrence: [PreTab GEMMs] then coop kernel (fallback: per-step) ----
  bool coop_ok = true;
  for (int c0 = 0; c0 < NSTEP; c0 += clen){
    int len = (c0 + clen <= NSTEP) ? clen : (NSTEP - c0);
    int gy  = (len + 127) / 128;
    gemmK<<<dim3(48, gy), dim3(256), 0, stream>>>(xh_all + (size_t)c0*512, W, area,
                                                  len, 6144, 512, b, 0, 0, 0, 0);
    gemmK<<<dim3(48, gy), dim3(256), 0, stream>>>(mask, V, area,
                                                  len, 6144, 512, nullptr, 0, 1, 1, c0);
    if (coop_ok){
      const float* Uv = U;  const float* Pv = area;  int c0v = c0, lenv = len;
      const float* Ghv = Gh; const float* dtv = dt;
      const float* Wev = We; const float* bev = be;
      const float* Wdv = Wd; const float* bdv = bd;
      float* hb = hbuf; float* rb = rhdbuf; float* hb2 = hpbuf; float* fb = featbuf;
      float* hd = HpDec;
      void* args[] = { &Uv, &Pv, &c0v, &lenv, &Ghv, &dtv, &Wev, &bev, &Wdv, &bdv,
                       &hb, &rb, &hb2, &fb, &hd };
      hipError_t err = hipLaunchCooperativeKernel((const void*)rnnCoopK,
                                                  dim3(256), dim3(256), args, 0, stream);
      if (err != hipSuccess) coop_ok = false;   // fall back for this + later chunks
    }
    if (!coop_ok){
      for (int sl = 0; sl < len; ++sl){
        int g = c0 + sl;
        if (g == 4096){
          mlp1K<<<dim3(16),  dim3(256), 0, stream>>>(hpbuf, We, be, featbuf);
          mlp2K<<<dim3(128), dim3(256), 0, stream>>>(featbuf, Wd, bd, hbuf);
        }
        int src = (g < 4096) ? g : (8190 - g);
        const float* prow  = area + (size_t)sl*6144;
        const float* ghrow = Gh + (size_t)src*2048;
        float* hpd = (g >= 4096) ? (HpDec + (size_t)(8190 - g)*2048) : nullptr;
        stepAK<<<dim3(256), dim3(256), 0, stream>>>(U, prow, ghrow, hbuf, zbuf, rhdbuf);
        stepBK<<<dim3(128), dim3(256), 0, stream>>>(U, prow + 4096, ghrow, dt + src,
                                                    zbuf, rhdbuf, hbuf, hpbuf, hpd);
      }
    }
  }

  // out = HpDec @ Wo + bo : 4095x512, K=2048 (HpDec stored pre-reversed)
  gemmK<<<dim3(4, 32), dim3(256), 0, stream>>>(HpDec, Wo, (float*)d_out,
                                               4095, 512, 2048, bo, 0, 0, 0, 0);
}

// Round 8
// 171111.829 us; speedup vs baseline: 2.8850x; 2.8850x over previous
//
#include <hip/hip_runtime.h>
#include <cmath>

// Problem dims (fixed): T=4096, I=512, H=2048, F=256
#define NSTEP 8191   // 4096 enc + 4095 dec
#define PROBE_ROUNDS 200
#define PROBE_SPIN (1 << 17)

// ---------------- small kernels ----------------
__global__ void fillK(float* p, int n, float v){
  for (int i = blockIdx.x*blockDim.x + threadIdx.x; i < n; i += gridDim.x*blockDim.x) p[i] = v;
}
__global__ void zeroIK(int* p, int n){
  int i = blockIdx.x*blockDim.x + threadIdx.x;
  if (i < n) p[i] = 0;
}
__global__ void copyK(float* dst, const float* __restrict__ src, int n){
  int i = blockIdx.x*blockDim.x + threadIdx.x;
  if (i < n) dst[i] = src[i];
}

// ---------------- sync-probes: bounded, output-independent, rocprof-readable ----
// probe 1: relaxed agent-scope atomic load/store flags (R3/R6 primitive class)
__global__ void probeRelK(int* flags, int* res){
  int w = blockIdx.x, t = threadIdx.x;      // 256 x 256
  int ok = 1;
  for (int r = 1; r <= PROBE_ROUNDS; ++r){
    __syncthreads();
    if (t == 0)
      __hip_atomic_store(flags + 32*w, r, __ATOMIC_RELAXED, __HIP_MEMORY_SCOPE_AGENT);
    int spin = 0;
    while (__hip_atomic_load(flags + 32*t, __ATOMIC_RELAXED, __HIP_MEMORY_SCOPE_AGENT) < r){
      if (++spin >= PROBE_SPIN){ ok = 0; break; }
      __builtin_amdgcn_s_sleep(2);
    }
    if (__syncthreads_or(!ok)){ if (t == 0) res[w] = -r; return; }
  }
  if (t == 0) res[w] = PROBE_ROUNDS;
}
// probe 2: RMW atomics (atomicExch publish, atomicOr-0 poll)
__global__ void probeRmwK(int* flags, int* res){
  int w = blockIdx.x, t = threadIdx.x;      // 256 x 256
  int ok = 1;
  for (int r = 1; r <= PROBE_ROUNDS; ++r){
    __syncthreads();
    if (t == 0) atomicExch(flags + 32*w, r);
    int spin = 0;
    while (atomicOr(flags + 32*t, 0) < r){
      if (++spin >= PROBE_SPIN){ ok = 0; break; }
      __builtin_amdgcn_s_sleep(2);
    }
    if (__syncthreads_or(!ok)){ if (t == 0) res[w] = -r; return; }
  }
  if (t == 0) res[w] = PROBE_ROUNDS;
}

// coalesced 2-pass mean
__global__ void mean1K(const float* __restrict__ seq, const float* __restrict__ mask,
                       float* __restrict__ Sp, float* __restrict__ Cp){
  int bb = blockIdx.x, i = threadIdx.x;      // 64 blocks x 512 threads
  float s = 0.f, c = 0.f;
  for (int tt = 64*bb; tt < 64*bb + 64; ++tt){
    size_t o = (size_t)tt*512 + i;
    s += seq[o];
    c += (mask[o] != 0.f) ? 1.f : 0.f;
  }
  Sp[bb*512 + i] = s; Cp[bb*512 + i] = c;
}
__global__ void mean2K(const float* __restrict__ Sp, const float* __restrict__ Cp,
                       float* __restrict__ meanv){
  int i = threadIdx.x;                        // 1 block x 512
  float s = 0.f, c = 0.f;
  for (int bb = 0; bb < 64; ++bb){ s += Sp[bb*512 + i]; c += Cp[bb*512 + i]; }
  meanv[i] = s / (1e-6f + c);
}

// ---------------- parallel affine scan for prex/xh recurrence ----------------
__device__ __forceinline__ void scan_ac(const float* __restrict__ Gx,
                                        const float* __restrict__ mask,
                                        const float* __restrict__ seq,
                                        float mn, int r, int i, float& a, float& c){
  int src = (r < 4096) ? r : (8190 - r);
  size_t o = (size_t)src*512 + i;
  float g = Gx[o], m = mask[o], x = seq[o];
  a = (1.f - m)*g;
  c = m*x + (1.f - m)*(1.f - g)*mn;
}
__global__ void scanSegK(const float* __restrict__ Gx, const float* __restrict__ mask,
                         const float* __restrict__ seq, const float* __restrict__ meanv,
                         float* __restrict__ segA, float* __restrict__ segC){
  int bb = blockIdx.x, i = threadIdx.x;       // 64 blocks x 512 threads
  float mn = meanv[i];
  float A = 1.f, C = 0.f;
  int r1 = 128*bb + 128; if (r1 > NSTEP) r1 = NSTEP;
  for (int r = 128*bb; r < r1; ++r){
    float a, c; scan_ac(Gx, mask, seq, mn, r, i, a, c);
    A = a*A; C = a*C + c;
  }
  segA[bb*512 + i] = A; segC[bb*512 + i] = C;
}
__global__ void scanFixK(const float* __restrict__ segA, const float* __restrict__ segC,
                         const float* __restrict__ prex0, float* __restrict__ segX0){
  int i = threadIdx.x;                        // 1 block x 512
  float x = prex0[i];
  for (int bb = 0; bb < 64; ++bb){
    segX0[bb*512 + i] = x;
    x = segA[bb*512 + i]*x + segC[bb*512 + i];
  }
}
__global__ void scanEmitK(const float* __restrict__ Gx, const float* __restrict__ mask,
                          const float* __restrict__ seq, const float* __restrict__ meanv,
                          const float* __restrict__ segX0, float* __restrict__ xh){
  int bb = blockIdx.x, i = threadIdx.x;
  float mn = meanv[i];
  float x = segX0[bb*512 + i];
  int r1 = 128*bb + 128; if (r1 > NSTEP) r1 = NSTEP;
  for (int r = 128*bb; r < r1; ++r){
    float a, c; scan_ac(Gx, mask, seq, mn, r, i, a, c);
    x = a*x + c;
    xh[(size_t)r*512 + i] = x;
  }
}

// ---------------- generic fp32 GEMM: C = act(A@B + bias) [+ C if beta] ----------
#define BM 128
#define BN 128
#define BK 8
__launch_bounds__(256)
__global__ void gemmK(const float* __restrict__ A, const float* __restrict__ B,
                      float* __restrict__ C, int M, int N, int K,
                      const float* __restrict__ bias, int act, int beta, int amap,
                      int rowoff){
  __shared__ float As[BK][BM+4];
  __shared__ float Bs[BK][BN+4];
  int tid = threadIdx.x;
  int r0 = blockIdx.y * BM, c0 = blockIdx.x * BN;
  int tr = tid >> 4, tc = tid & 15;
  int ar = tid >> 1, ak = (tid & 1)*4;
  int bkr = tid >> 5, bkc = (tid & 31)*4;
  float acc[8][8] = {};

  for (int k0 = 0; k0 < K; k0 += BK){
    int r = r0 + ar;
    float4 av = make_float4(0.f,0.f,0.f,0.f);
    if (r < M){
      int g = rowoff + r;
      int rs = amap ? (g < 4096 ? g : 8190 - g) : r;
      av = *(const float4*)(A + (size_t)rs*K + k0 + ak);
    }
    As[ak+0][ar] = av.x; As[ak+1][ar] = av.y; As[ak+2][ar] = av.z; As[ak+3][ar] = av.w;
    *(float4*)(&Bs[bkr][bkc]) = *(const float4*)(B + (size_t)(k0 + bkr)*N + c0 + bkc);
    __syncthreads();
    #pragma unroll
    for (int kk = 0; kk < BK; ++kk){
      float a[8], bb[8];
      #pragma unroll
      for (int i = 0; i < 8; ++i) a[i]  = As[kk][tr*8 + i];
      #pragma unroll
      for (int j = 0; j < 8; ++j) bb[j] = Bs[kk][tc*8 + j];
      #pragma unroll
      for (int i = 0; i < 8; ++i)
        #pragma unroll
        for (int j = 0; j < 8; ++j)
          acc[i][j] += a[i]*bb[j];
    }
    __syncthreads();
  }

  #pragma unroll
  for (int i = 0; i < 8; ++i){
    int r = r0 + tr*8 + i;
    if (r >= M) continue;
    float v[8];
    #pragma unroll
    for (int j = 0; j < 8; ++j){
      int c = c0 + tc*8 + j;
      float x = acc[i][j];
      if (bias) x += bias[c];
      if (act == 1) x = expf(-fmaxf(x, 0.f));
      v[j] = x;
    }
    float* cp = C + (size_t)r*N + c0 + tc*8;
    if (beta){
      float4 o0 = *(const float4*)(cp);
      float4 o1 = *(const float4*)(cp + 4);
      v[0]+=o0.x; v[1]+=o0.y; v[2]+=o0.z; v[3]+=o0.w;
      v[4]+=o1.x; v[5]+=o1.y; v[6]+=o1.z; v[7]+=o1.w;
    }
    *(float4*)(cp)     = make_float4(v[0],v[1],v[2],v[3]);
    *(float4*)(cp + 4) = make_float4(v[4],v[5],v[6],v[7]);
  }
}

// ---------------- per-step kernels: 32-col panels, line-perfect U reads --------
// stepA: zr = sigmoid(pre + (gh*h)@U[:, :4096]); writes z(2048), rhd=r*hd(2048).
// 128 WGs x 512 thr; WG w owns j in [32w, 32w+32) of the 4096-wide zr space.
// thread t: jo=t&31, ko=t>>5; k = q*16+ko, q=0..127. A wave's loads for fixed q
// cover 2 rows x 128B contiguous -> 2 full cache lines, zero over-fetch.
__launch_bounds__(512)
__global__ void stepAK(const float* __restrict__ U, const float* __restrict__ pre,
                       const float* __restrict__ ghrow, const float* __restrict__ hbuf,
                       float* __restrict__ zbuf, float* __restrict__ rhdbuf){
  __shared__ float hdl[2048];
  __shared__ float red[16][33];
  int w = blockIdx.x, t = threadIdx.x;
  for (int i = t; i < 2048; i += 512) hdl[i] = hbuf[i] * ghrow[i];
  __syncthreads();
  int jo = t & 31, ko = t >> 5;
  const float* Up = U + (size_t)ko*6144 + 32*w + jo;
  float s = 0.f;
  #pragma unroll 8
  for (int q = 0; q < 128; ++q)
    s += hdl[q*16 + ko] * Up[(size_t)q*16*6144];
  red[ko][jo] = s;
  __syncthreads();
  if (t < 32){
    float a = 0.f;
    #pragma unroll
    for (int q = 0; q < 16; ++q) a += red[q][t];
    int j = 32*w + t;
    float v = 1.f/(1.f + expf(-(pre[j] + a)));
    if (j < 2048) zbuf[j] = v;
    else          rhdbuf[j - 2048] = v * hdl[j - 2048];
  }
}

// stepB: htil = tanh(prh + rhd@U[:, 4096:]); h += dt*dh; hp out (+HpDec if dec).
// 64 WGs x 512 thr; WG w owns j in [32w, 32w+32) of 2048.
__launch_bounds__(512)
__global__ void stepBK(const float* __restrict__ U, const float* __restrict__ prh,
                       const float* __restrict__ ghrow, const float* __restrict__ dtp,
                       const float* __restrict__ zbuf, const float* __restrict__ rhdbuf,
                       float* __restrict__ hbuf, float* __restrict__ hpbuf,
                       float* __restrict__ hpdec){
  __shared__ float rl[2048];
  __shared__ float red[16][33];
  int w = blockIdx.x, t = threadIdx.x;
  for (int i = t; i < 2048; i += 512) rl[i] = rhdbuf[i];
  __syncthreads();
  int jo = t & 31, ko = t >> 5;
  const float* Up = U + (size_t)ko*6144 + 4096 + 32*w + jo;
  float s = 0.f;
  #pragma unroll 8
  for (int q = 0; q < 128; ++q)
    s += rl[q*16 + ko] * Up[(size_t)q*16*6144];
  red[ko][jo] = s;
  __syncthreads();
  if (t < 32){
    float a = 0.f;
    #pragma unroll
    for (int q = 0; q < 16; ++q) a += red[q][t];
    int j = 32*w + t;
    float htil = tanhf(prh[j] + a);
    float z    = zbuf[j];
    float hold = hbuf[j];
    float hd   = hold * ghrow[j];
    float hp   = z*hd + (1.f - z)*htil;
    float dh   = (1.f - z)*(htil - hd);
    hbuf[j]  = hold + dtp[0]*dh;
    hpbuf[j] = hp;
    if (hpdec) hpdec[j] = hp;
  }
}

// mid-MLP kernel 1: feature[f] = relu( relu(hp) @ We + be )  (F=256, K=2048)
__launch_bounds__(256)
__global__ void mlp1K(const float* __restrict__ hpbuf, const float* __restrict__ We,
                      const float* __restrict__ be, float* __restrict__ featbuf){
  __shared__ float red[16][17];
  int w = blockIdx.x, t = threadIdx.x;      // 16 WGs
  int fo = t & 15, ko = t >> 4;
  int f = 16*w + fo;
  float s = 0.f;
  int k0 = ko*128;
  for (int k = k0; k < k0 + 128; ++k)
    s += fmaxf(hpbuf[k], 0.f) * We[(size_t)k*256 + f];
  red[ko][fo] = s;
  __syncthreads();
  if (t < 16){
    float a = 0.f;
    #pragma unroll
    for (int q = 0; q < 16; ++q) a += red[q][t];
    featbuf[16*w + t] = fmaxf(a + be[16*w + t], 0.f);
  }
}
// mid-MLP kernel 2: h[j] = feature @ Wd + bd  (H=2048, K=256)
__launch_bounds__(256)
__global__ void mlp2K(const float* __restrict__ featbuf, const float* __restrict__ Wd,
                      const float* __restrict__ bd, float* __restrict__ hbuf){
  __shared__ float red[16][17];
  int w = blockIdx.x, t = threadIdx.x;      // 128 WGs
  int jo = t & 15, ko = t >> 4;
  int j = 16*w + jo;
  float s = 0.f;
  int k0 = ko*16;
  for (int k = k0; k < k0 + 16; ++k)
    s += featbuf[k] * Wd[(size_t)k*2048 + j];
  red[ko][jo] = s;
  __syncthreads();
  if (t < 16){
    float a = 0.f;
    #pragma unroll
    for (int q = 0; q < 16; ++q) a += red[q][t];
    hbuf[16*w + t] = a + bd[16*w + t];
  }
}

// ---------------- launch ----------------
extern "C" void kernel_launch(void* const* d_in, const int* in_sizes, int n_in,
                              void* d_out, int out_size, void* d_ws, size_t ws_size,
                              hipStream_t stream){
  (void)in_sizes; (void)n_in;
  const float* seq   = (const float*)d_in[0];
  const float* mask  = (const float*)d_in[1];
  const float* delta = (const float*)d_in[2];
  const float* dt    = (const float*)d_in[3];
  const float* h0    = (const float*)d_in[4];
  /* d_in[5] = dh0: carried dh never read by the reference cell */
  const float* prex0 = (const float*)d_in[6];
  const float* Wgx   = (const float*)d_in[7];
  const float* bgx   = (const float*)d_in[8];
  const float* Wgh   = (const float*)d_in[9];
  const float* bgh   = (const float*)d_in[10];
  const float* W     = (const float*)d_in[11];
  const float* U     = (const float*)d_in[12];
  const float* V     = (const float*)d_in[13];
  const float* b     = (const float*)d_in[14];
  const float* We    = (const float*)d_in[15];
  const float* be    = (const float*)d_in[16];
  const float* Wd    = (const float*)d_in[17];
  const float* bd    = (const float*)d_in[18];
  const float* Wo    = (const float*)d_in[19];
  const float* bo    = (const float*)d_in[20];

  float* wsf = (float*)d_ws;
  size_t wsFloats = ws_size / 4;
  size_t off = 0;
  float* meanv  = wsf + off;  off += 512;
  float* hbuf   = wsf + off;  off += 2048;
  float* zbuf   = wsf + off;  off += 2048;
  float* rhdbuf = wsf + off;  off += 2048;
  float* hpbuf  = wsf + off;  off += 2048;
  float* featbuf= wsf + off;  off += 256;
  float* Sp     = wsf + off;  off += (size_t)64*512;   // also hosts probe scratch
  float* Cp     = wsf + off;  off += (size_t)64*512;
  float* Gh     = wsf + off;  off += (size_t)4096*2048;
  float* xh_all = wsf + off;  off += (size_t)NSTEP*512;
  float* HpDec  = wsf + off;  off += (size_t)4095*2048;
  size_t fixedF = off;

  // chunk area: overlays {Gx, scan temps} during precompute, PreTab chunk after
  float* area  = wsf + fixedF;
  float* Gx    = area;                                   // 4096*512
  float* segA  = area + (size_t)4096*512;                // 64*512
  float* segC  = segA + (size_t)64*512;
  float* segX0 = segC + (size_t)64*512;
  size_t preNeed = (size_t)4096*512 + (size_t)3*64*512;

  size_t areaF = (wsFloats > fixedF) ? (wsFloats - fixedF) : 0;
  long chunkSteps = (long)(areaF / 6144);
  if (areaF < preNeed || chunkSteps < 64){
    fillK<<<dim3(256), dim3(256), 0, stream>>>((float*)d_out, out_size,
                                               1.0e6f + (float)(ws_size >> 20));
    return;
  }
  if (chunkSteps > NSTEP) chunkSteps = NSTEP;
  int nch  = (int)((NSTEP + chunkSteps - 1) / chunkSteps);
  int clen = (NSTEP + nch - 1) / nch;

  // ---- sync probes (bounded; results to scratch; read via rocprof durations) ----
  int* probe = (int*)Sp;          // pf1[8192] res1[256] pf2[8192] res2[256]
  zeroIK<<<dim3(68), dim3(256), 0, stream>>>(probe, 16896);
  probeRelK<<<dim3(256), dim3(256), 0, stream>>>(probe, probe + 8192);
  probeRmwK<<<dim3(256), dim3(256), 0, stream>>>(probe + 8448, probe + 16640);

  // ---- precompute ----
  mean1K<<<dim3(64), dim3(512), 0, stream>>>(seq, mask, Sp, Cp);
  mean2K<<<dim3(1),  dim3(512), 0, stream>>>(Sp, Cp, meanv);
  gemmK<<<dim3(4, 32),  dim3(256), 0, stream>>>(delta, Wgx, Gx, 4096, 512, 512, bgx, 1, 0, 0, 0);
  gemmK<<<dim3(16, 32), dim3(256), 0, stream>>>(delta, Wgh, Gh, 4096, 2048, 512, bgh, 1, 0, 0, 0);
  scanSegK<<<dim3(64), dim3(512), 0, stream>>>(Gx, mask, seq, meanv, segA, segC);
  scanFixK<<<dim3(1),  dim3(512), 0, stream>>>(segA, segC, prex0, segX0);
  scanEmitK<<<dim3(64), dim3(512), 0, stream>>>(Gx, mask, seq, meanv, segX0, xh_all);
  copyK<<<dim3(8), dim3(256), 0, stream>>>(hbuf, h0, 2048);

  // ---- chunked recurrence: [PreTab GEMMs] then per-step kernel pairs ----
  for (int c0 = 0; c0 < NSTEP; c0 += clen){
    int len = (c0 + clen <= NSTEP) ? clen : (NSTEP - c0);
    int gy  = (len + 127) / 128;
    gemmK<<<dim3(48, gy), dim3(256), 0, stream>>>(xh_all + (size_t)c0*512, W, area,
                                                  len, 6144, 512, b, 0, 0, 0, 0);
    gemmK<<<dim3(48, gy), dim3(256), 0, stream>>>(mask, V, area,
                                                  len, 6144, 512, nullptr, 0, 1, 1, c0);
    for (int sl = 0; sl < len; ++sl){
      int g = c0 + sl;
      if (g == 4096){
        mlp1K<<<dim3(16),  dim3(256), 0, stream>>>(hpbuf, We, be, featbuf);
        mlp2K<<<dim3(128), dim3(256), 0, stream>>>(featbuf, Wd, bd, hbuf);
      }
      int src = (g < 4096) ? g : (8190 - g);
      const float* prow  = area + (size_t)sl*6144;
      const float* ghrow = Gh + (size_t)src*2048;
      float* hpd = (g >= 4096) ? (HpDec + (size_t)(8190 - g)*2048) : nullptr;
      stepAK<<<dim3(128), dim3(512), 0, stream>>>(U, prow, ghrow, hbuf, zbuf, rhdbuf);
      stepBK<<<dim3(64),  dim3(512), 0, stream>>>(U, prow + 4096, ghrow, dt + src,
                                                  zbuf, rhdbuf, hbuf, hpbuf, hpd);
    }
  }

  // out = HpDec @ Wo + bo : 4095x512, K=2048 (HpDec stored pre-reversed)
  gemmK<<<dim3(4, 32), dim3(256), 0, stream>>>(HpDec, Wo, (float*)d_out,
                                               4095, 512, 2048, bo, 0, 0, 0, 0);
}

// Round 9
// 142693.103 us; speedup vs baseline: 3.4595x; 1.1992x over previous
//
#include <hip/hip_runtime.h>
#include <cmath>

// Problem dims (fixed): T=4096, I=512, H=2048, F=256
#define NSTEP 8191   // 4096 enc + 4095 dec
#define WAIT_SPIN (1 << 15)
#define ARR_SPIN  (1 << 14)

// ---------------- cross-WG primitives: atomic RMW only (device-coherent) ------
__device__ __forceinline__ int   rmwLoadI (int* p){ return atomicOr(p, 0); }
__device__ __forceinline__ void  rmwStoreI(int* p, int v){ atomicExch(p, v); }
__device__ __forceinline__ float rmwLoadF (float* p){
  return __int_as_float(atomicOr((int*)p, 0));
}
__device__ __forceinline__ void  rmwStoreF(float* p, float v){
  atomicExch((int*)p, __float_as_int(v));
}

// pub line layout (per WG, 32 ints = 128B): [0]=flagB [1]=flagA
// [8..15]=h slice (float bits) [16..23]=rhd slice. Thread t polls line t only
// (the exact k-slice it consumes) -> no over-waiting, minimal contention.
__device__ __forceinline__ int waitAll(int* pubI, int which, int e){
  const int t = threadIdx.x;
  int* f = pubI + t*32 + which;
  int to = 0, spin = 0;
  while (rmwLoadI(f) < e){
    if (++spin >= WAIT_SPIN){ to = 1; break; }
    __builtin_amdgcn_s_sleep(1);
  }
  int bad = __syncthreads_or(to);
  asm volatile("" ::: "memory");
  return !bad;
}
// __syncthreads drains vmcnt => payload RMWs reached the coherence point before
// the flag RMW issues. Consumer observed flag>=e => payload RMW-reads see data.
__device__ __forceinline__ void pubFlag(int* pubI, int w, int which, int e){
  __syncthreads();
  if (threadIdx.x == 0) rmwStoreI(pubI + w*32 + which, e);
}

// ---------------- small kernels ----------------
__global__ void fillK(float* p, int n, float v){
  for (int i = blockIdx.x*blockDim.x + threadIdx.x; i < n; i += gridDim.x*blockDim.x) p[i] = v;
}

// per-call init: zero flags+ctrl, publish h0 to pub lines AND hbuf (deterministic)
__global__ void initK(int* pubI, int* ctrl, const float* __restrict__ h0,
                      float* __restrict__ hbuf){
  int t = threadIdx.x;   // 1 block x 256
  pubI[t*32 + 0] = 0;
  pubI[t*32 + 1] = 0;
  #pragma unroll
  for (int j = 0; j < 8; ++j){
    pubI[t*32 + 8 + j] = __float_as_int(h0[8*t + j]);
    hbuf[8*t + j] = h0[8*t + j];
  }
  for (int i = t; i < 1024; i += 256) ctrl[i] = 0;
}

// chunk-boundary state reconciliation: canonical h -> both stores; reset flags.
__global__ void syncStateK(int* pubI, float* __restrict__ hbuf, int* done_prev){
  int t = threadIdx.x;   // 1 block x 256
  int dp = *done_prev;
  #pragma unroll
  for (int j = 0; j < 8; ++j){
    if (dp) hbuf[8*t + j] = __int_as_float(pubI[t*32 + 8 + j]);
    else    pubI[t*32 + 8 + j] = __float_as_int(hbuf[8*t + j]);
  }
  pubI[t*32 + 0] = 0;
  pubI[t*32 + 1] = 0;
}

// coalesced 2-pass mean
__global__ void mean1K(const float* __restrict__ seq, const float* __restrict__ mask,
                       float* __restrict__ Sp, float* __restrict__ Cp){
  int bb = blockIdx.x, i = threadIdx.x;      // 64 blocks x 512 threads
  float s = 0.f, c = 0.f;
  for (int tt = 64*bb; tt < 64*bb + 64; ++tt){
    size_t o = (size_t)tt*512 + i;
    s += seq[o];
    c += (mask[o] != 0.f) ? 1.f : 0.f;
  }
  Sp[bb*512 + i] = s; Cp[bb*512 + i] = c;
}
__global__ void mean2K(const float* __restrict__ Sp, const float* __restrict__ Cp,
                       float* __restrict__ meanv){
  int i = threadIdx.x;                        // 1 block x 512
  float s = 0.f, c = 0.f;
  for (int bb = 0; bb < 64; ++bb){ s += Sp[bb*512 + i]; c += Cp[bb*512 + i]; }
  meanv[i] = s / (1e-6f + c);
}

// ---------------- parallel affine scan for prex/xh recurrence ----------------
__device__ __forceinline__ void scan_ac(const float* __restrict__ Gx,
                                        const float* __restrict__ mask,
                                        const float* __restrict__ seq,
                                        float mn, int r, int i, float& a, float& c){
  int src = (r < 4096) ? r : (8190 - r);
  size_t o = (size_t)src*512 + i;
  float g = Gx[o], m = mask[o], x = seq[o];
  a = (1.f - m)*g;
  c = m*x + (1.f - m)*(1.f - g)*mn;
}
__global__ void scanSegK(const float* __restrict__ Gx, const float* __restrict__ mask,
                         const float* __restrict__ seq, const float* __restrict__ meanv,
                         float* __restrict__ segA, float* __restrict__ segC){
  int bb = blockIdx.x, i = threadIdx.x;       // 64 blocks x 512 threads
  float mn = meanv[i];
  float A = 1.f, C = 0.f;
  int r1 = 128*bb + 128; if (r1 > NSTEP) r1 = NSTEP;
  for (int r = 128*bb; r < r1; ++r){
    float a, c; scan_ac(Gx, mask, seq, mn, r, i, a, c);
    A = a*A; C = a*C + c;
  }
  segA[bb*512 + i] = A; segC[bb*512 + i] = C;
}
__global__ void scanFixK(const float* __restrict__ segA, const float* __restrict__ segC,
                         const float* __restrict__ prex0, float* __restrict__ segX0){
  int i = threadIdx.x;                        // 1 block x 512
  float x = prex0[i];
  for (int bb = 0; bb < 64; ++bb){
    segX0[bb*512 + i] = x;
    x = segA[bb*512 + i]*x + segC[bb*512 + i];
  }
}
__global__ void scanEmitK(const float* __restrict__ Gx, const float* __restrict__ mask,
                          const float* __restrict__ seq, const float* __restrict__ meanv,
                          const float* __restrict__ segX0, float* __restrict__ xh){
  int bb = blockIdx.x, i = threadIdx.x;
  float mn = meanv[i];
  float x = segX0[bb*512 + i];
  int r1 = 128*bb + 128; if (r1 > NSTEP) r1 = NSTEP;
  for (int r = 128*bb; r < r1; ++r){
    float a, c; scan_ac(Gx, mask, seq, mn, r, i, a, c);
    x = a*x + c;
    xh[(size_t)r*512 + i] = x;
  }
}

// ---------------- generic fp32 GEMM: C = act(A@B + bias) [+ C if beta] ----------
#define BM 128
#define BN 128
#define BK 8
__launch_bounds__(256)
__global__ void gemmK(const float* __restrict__ A, const float* __restrict__ B,
                      float* __restrict__ C, int M, int N, int K,
                      const float* __restrict__ bias, int act, int beta, int amap,
                      int rowoff){
  __shared__ float As[BK][BM+4];
  __shared__ float Bs[BK][BN+4];
  int tid = threadIdx.x;
  int r0 = blockIdx.y * BM, c0 = blockIdx.x * BN;
  int tr = tid >> 4, tc = tid & 15;
  int ar = tid >> 1, ak = (tid & 1)*4;
  int bkr = tid >> 5, bkc = (tid & 31)*4;
  float acc[8][8] = {};

  for (int k0 = 0; k0 < K; k0 += BK){
    int r = r0 + ar;
    float4 av = make_float4(0.f,0.f,0.f,0.f);
    if (r < M){
      int g = rowoff + r;
      int rs = amap ? (g < 4096 ? g : 8190 - g) : r;
      av = *(const float4*)(A + (size_t)rs*K + k0 + ak);
    }
    As[ak+0][ar] = av.x; As[ak+1][ar] = av.y; As[ak+2][ar] = av.z; As[ak+3][ar] = av.w;
    *(float4*)(&Bs[bkr][bkc]) = *(const float4*)(B + (size_t)(k0 + bkr)*N + c0 + bkc);
    __syncthreads();
    #pragma unroll
    for (int kk = 0; kk < BK; ++kk){
      float a[8], bb[8];
      #pragma unroll
      for (int i = 0; i < 8; ++i) a[i]  = As[kk][tr*8 + i];
      #pragma unroll
      for (int j = 0; j < 8; ++j) bb[j] = Bs[kk][tc*8 + j];
      #pragma unroll
      for (int i = 0; i < 8; ++i)
        #pragma unroll
        for (int j = 0; j < 8; ++j)
          acc[i][j] += a[i]*bb[j];
    }
    __syncthreads();
  }

  #pragma unroll
  for (int i = 0; i < 8; ++i){
    int r = r0 + tr*8 + i;
    if (r >= M) continue;
    float v[8];
    #pragma unroll
    for (int j = 0; j < 8; ++j){
      int c = c0 + tc*8 + j;
      float x = acc[i][j];
      if (bias) x += bias[c];
      if (act == 1) x = expf(-fmaxf(x, 0.f));
      v[j] = x;
    }
    float* cp = C + (size_t)r*N + c0 + tc*8;
    if (beta){
      float4 o0 = *(const float4*)(cp);
      float4 o1 = *(const float4*)(cp + 4);
      v[0]+=o0.x; v[1]+=o0.y; v[2]+=o0.z; v[3]+=o0.w;
      v[4]+=o1.x; v[5]+=o1.y; v[6]+=o1.z; v[7]+=o1.w;
    }
    *(float4*)(cp)     = make_float4(v[0],v[1],v[2],v[3]);
    *(float4*)(cp + 4) = make_float4(v[4],v[5],v[6],v[7]);
  }
}

// ---------------- persistent chunk kernel (plain launch, RMW dataflow) ---------
// 256 WGs x 256 thr, 1 WG/CU. WG w owns output cols [8w,8w+8); thread t owns
// k-slice [8t,8t+8). U register-resident. Events per-chunk from 0. On ANY
// timeout -> return with done=0 (fallback chain recomputes the chunk).
__launch_bounds__(256, 1)
__global__ void rnnPersK(const float* __restrict__ U, const float* __restrict__ PreC,
                         int c0, int len,
                         const float* __restrict__ Gh, const float* __restrict__ dts,
                         const float* __restrict__ We, const float* __restrict__ be,
                         const float* __restrict__ Wd, const float* __restrict__ bd,
                         int* pubI, float* hpbuf, float* featbuf,
                         float* __restrict__ HpDec, int* arrival, int* done){
  const int w = blockIdx.x;
  const int t = threadIdx.x;
  const int lane = t & 63, wv = t >> 6;
  __shared__ float redA[4][8], redB[4][8], redH[4][8], ldsH[8], ldsHd[8];
  __shared__ int okArr;

  // residency check: all 256 WGs must arrive, else bail (done stays 0)
  if (t == 0){
    atomicAdd(arrival, 1);
    int ok = 1, spin = 0;
    while (atomicOr(arrival, 0) < 256){
      if (++spin >= ARR_SPIN){ ok = 0; break; }
      __builtin_amdgcn_s_sleep(2);
    }
    okArr = ok;
  }
  __syncthreads();
  if (!okArr) return;

  // register-resident U slices: uz/ur/uh[cc][i] = U[8t+i][{0,2048,4096}+8w+cc]
  float uz[8][8], ur[8][8], uh[8][8];
  #pragma unroll
  for (int i = 0; i < 8; ++i){
    const float* row = U + (size_t)(8*t + i)*6144 + 8*w;
    #pragma unroll
    for (int cc = 0; cc < 8; ++cc){
      uz[cc][i] = row[cc];
      ur[cc][i] = row[2048 + cc];
      uh[cc][i] = row[4096 + cc];
    }
  }

  int e = 0;
  float ghn[8]; float pzn = 0.f, prn = 0.f, phn = 0.f, dtn = 0.f;
  auto prefetch = [&](int g){
    int src = (g < 4096) ? g : (8190 - g);
    const float* gr = Gh + (size_t)src*2048 + 8*t;
    #pragma unroll
    for (int i = 0; i < 8; ++i) ghn[i] = gr[i];
    const float* prow = PreC + (size_t)(g - c0)*6144;
    if (t < 8){ pzn = prow[8*w + t]; phn = prow[4096 + 8*w + t]; dtn = dts[src]; }
    else if (t < 16){ prn = prow[2048 + 8*w + (t - 8)]; }
  };
  prefetch(c0);

  for (int sl = 0; sl < len; ++sl){
    int g = c0 + sl;

    if (g == 4096){
      // ---- mid MLP: h = relu(relu(hp)@We + be) @ Wd + bd ----
      if (!waitAll(pubI, 0, e)) return;            // hp(4095) ready everywhere
      {
        float part = 0.f;
        #pragma unroll
        for (int i = 0; i < 8; ++i){
          float hp = fmaxf(rmwLoadF(hpbuf + 8*t + i), 0.f);
          part += hp * We[(size_t)(8*t + i)*256 + w];
        }
        #pragma unroll
        for (int o = 32; o; o >>= 1) part += __shfl_down(part, o);
        if (lane == 0) redA[wv][0] = part;
        __syncthreads();
        if (t == 0)
          rmwStoreF(featbuf + w,
                    fmaxf(redA[0][0]+redA[1][0]+redA[2][0]+redA[3][0] + be[w], 0.f));
      }
      ++e; pubFlag(pubI, w, 1, e);                 // flagA: feature slice ready
      if (!waitAll(pubI, 1, e)) return;
      {
        float fv = rmwLoadF(featbuf + t);
        #pragma unroll
        for (int cc = 0; cc < 8; ++cc){
          float v = fv * Wd[(size_t)t*2048 + 8*w + cc];
          #pragma unroll
          for (int o = 32; o; o >>= 1) v += __shfl_down(v, o);
          if (lane == 0) redB[wv][cc] = v;
        }
        __syncthreads();
        if (t < 8)
          rmwStoreI(pubI + w*32 + 8 + t,
                    __float_as_int(redB[0][t]+redB[1][t]+redB[2][t]+redB[3][t] + bd[8*w + t]));
      }
      ++e; pubFlag(pubI, w, 0, e);                 // flagB: decoder h0 published
    }

    if (!waitAll(pubI, 0, e)) return;              // flagB: h for this step ready

    {
      float ghc[8];
      #pragma unroll
      for (int i = 0; i < 8; ++i) ghc[i] = ghn[i];
      float pz = pzn, pr = prn, ph = phn, dtv = dtn;

      // ---------- phase A: z,r = sigmoid(pre + (gh*h)@U1) ----------
      float hd[8];
      #pragma unroll
      for (int i = 0; i < 8; ++i){
        float hv = __int_as_float(rmwLoadI(pubI + t*32 + 8 + i));  // h slice, line t
        hd[i] = hv * ghc[i];
        if (t == w){ ldsH[i] = hv; ldsHd[i] = hd[i]; }
      }
      if (sl + 1 < len) prefetch(g + 1);

      float accz[8], accr[8];
      #pragma unroll
      for (int cc = 0; cc < 8; ++cc){
        float az = 0.f, ar_ = 0.f;
        #pragma unroll
        for (int i = 0; i < 8; ++i){ az += hd[i]*uz[cc][i]; ar_ += hd[i]*ur[cc][i]; }
        accz[cc] = az; accr[cc] = ar_;
      }
      #pragma unroll
      for (int cc = 0; cc < 8; ++cc){
        float v = accz[cc];
        #pragma unroll
        for (int o = 32; o; o >>= 1) v += __shfl_down(v, o);
        if (lane == 0) redA[wv][cc] = v;
        v = accr[cc];
        #pragma unroll
        for (int o = 32; o; o >>= 1) v += __shfl_down(v, o);
        if (lane == 0) redB[wv][cc] = v;
      }
      __syncthreads();
      float zreg = 0.f;
      if (t < 8){
        float s = redA[0][t]+redA[1][t]+redA[2][t]+redA[3][t] + pz;
        zreg = 1.f/(1.f + expf(-s));               // carried in register into phase B
      } else if (t < 16){
        int cc = t - 8;
        float s = redB[0][cc]+redB[1][cc]+redB[2][cc]+redB[3][cc] + pr;
        float r = 1.f/(1.f + expf(-s));
        rmwStoreI(pubI + w*32 + 16 + cc, __float_as_int(r * ldsHd[cc]));
      }
      ++e; pubFlag(pubI, w, 1, e);                 // flagA: rhd slice published
      if (!waitAll(pubI, 1, e)) return;

      // ---------- phase B: htil = tanh(pre_h + (r*hd)@U2); h update ----------
      float rvv[8];
      #pragma unroll
      for (int i = 0; i < 8; ++i)
        rvv[i] = __int_as_float(rmwLoadI(pubI + t*32 + 16 + i));
      float acch[8];
      #pragma unroll
      for (int cc = 0; cc < 8; ++cc){
        float a = 0.f;
        #pragma unroll
        for (int i = 0; i < 8; ++i) a += rvv[i]*uh[cc][i];
        acch[cc] = a;
      }
      #pragma unroll
      for (int cc = 0; cc < 8; ++cc){
        float v = acch[cc];
        #pragma unroll
        for (int o = 32; o; o >>= 1) v += __shfl_down(v, o);
        if (lane == 0) redH[wv][cc] = v;
      }
      __syncthreads();
      if (t < 8){
        float u    = redH[0][t]+redH[1][t]+redH[2][t]+redH[3][t] + ph;
        float htil = tanhf(u);
        float z = zreg, hdv = ldsHd[t], hold = ldsH[t];
        float hp = z*hdv + (1.f - z)*htil;
        float dh = (1.f - z)*(htil - hdv);
        rmwStoreI(pubI + w*32 + 8 + t, __float_as_int(hold + dtv*dh));  // h carry
        rmwStoreF(hpbuf + 8*w + t, hp);
        if (g >= 4096) HpDec[(size_t)(8190 - g)*2048 + 8*w + t] = hp;   // pre-reversed
      }
      ++e; pubFlag(pubI, w, 0, e);                 // flagB: h/hp published
    }
  }

  // success: all lines reached final event => every WG completed every step
  if (w == 0){
    if (waitAll(pubI, 0, e)){
      if (t == 0) atomicExch(done, 1);
    }
  }
}

// ---------------- fallback per-step kernels (early-exit if persistent won) -----
__launch_bounds__(512)
__global__ void stepAK(const int* __restrict__ done,
                       const float* __restrict__ U, const float* __restrict__ pre,
                       const float* __restrict__ ghrow, const float* __restrict__ hbuf,
                       float* __restrict__ zbuf, float* __restrict__ rhdbuf){
  if (*done) return;
  __shared__ float hdl[2048];
  __shared__ float red[16][33];
  int w = blockIdx.x, t = threadIdx.x;
  for (int i = t; i < 2048; i += 512) hdl[i] = hbuf[i] * ghrow[i];
  __syncthreads();
  int jo = t & 31, ko = t >> 5;
  const float* Up = U + (size_t)ko*6144 + 32*w + jo;
  float s = 0.f;
  #pragma unroll 8
  for (int q = 0; q < 128; ++q)
    s += hdl[q*16 + ko] * Up[(size_t)q*16*6144];
  red[ko][jo] = s;
  __syncthreads();
  if (t < 32){
    float a = 0.f;
    #pragma unroll
    for (int q = 0; q < 16; ++q) a += red[q][t];
    int j = 32*w + t;
    float v = 1.f/(1.f + expf(-(pre[j] + a)));
    if (j < 2048) zbuf[j] = v;
    else          rhdbuf[j - 2048] = v * hdl[j - 2048];
  }
}

__launch_bounds__(512)
__global__ void stepBK(const int* __restrict__ done,
                       const float* __restrict__ U, const float* __restrict__ prh,
                       const float* __restrict__ ghrow, const float* __restrict__ dtp,
                       const float* __restrict__ zbuf, const float* __restrict__ rhdbuf,
                       float* __restrict__ hbuf, float* __restrict__ hpbuf,
                       float* __restrict__ hpdec){
  if (*done) return;
  __shared__ float rl[2048];
  __shared__ float red[16][33];
  int w = blockIdx.x, t = threadIdx.x;
  for (int i = t; i < 2048; i += 512) rl[i] = rhdbuf[i];
  __syncthreads();
  int jo = t & 31, ko = t >> 5;
  const float* Up = U + (size_t)ko*6144 + 4096 + 32*w + jo;
  float s = 0.f;
  #pragma unroll 8
  for (int q = 0; q < 128; ++q)
    s += rl[q*16 + ko] * Up[(size_t)q*16*6144];
  red[ko][jo] = s;
  __syncthreads();
  if (t < 32){
    float a = 0.f;
    #pragma unroll
    for (int q = 0; q < 16; ++q) a += red[q][t];
    int j = 32*w + t;
    float htil = tanhf(prh[j] + a);
    float z    = zbuf[j];
    float hold = hbuf[j];
    float hd   = hold * ghrow[j];
    float hp   = z*hd + (1.f - z)*htil;
    float dh   = (1.f - z)*(htil - hd);
    hbuf[j]  = hold + dtp[0]*dh;
    hpbuf[j] = hp;
    if (hpdec) hpdec[j] = hp;
  }
}

__launch_bounds__(256)
__global__ void mlp1K(const int* __restrict__ done,
                      const float* __restrict__ hpbuf, const float* __restrict__ We,
                      const float* __restrict__ be, float* __restrict__ featbuf){
  if (*done) return;
  __shared__ float red[16][17];
  int w = blockIdx.x, t = threadIdx.x;      // 16 WGs
  int fo = t & 15, ko = t >> 4;
  int f = 16*w + fo;
  float s = 0.f;
  int k0 = ko*128;
  for (int k = k0; k < k0 + 128; ++k)
    s += fmaxf(hpbuf[k], 0.f) * We[(size_t)k*256 + f];
  red[ko][fo] = s;
  __syncthreads();
  if (t < 16){
    float a = 0.f;
    #pragma unroll
    for (int q = 0; q < 16; ++q) a += red[q][t];
    featbuf[16*w + t] = fmaxf(a + be[16*w + t], 0.f);
  }
}
__launch_bounds__(256)
__global__ void mlp2K(const int* __restrict__ done,
                      const float* __restrict__ featbuf, const float* __restrict__ Wd,
                      const float* __restrict__ bd, float* __restrict__ hbuf){
  if (*done) return;
  __shared__ float red[16][17];
  int w = blockIdx.x, t = threadIdx.x;      // 128 WGs
  int jo = t & 15, ko = t >> 4;
  int j = 16*w + jo;
  float s = 0.f;
  int k0 = ko*16;
  for (int k = k0; k < k0 + 16; ++k)
    s += featbuf[k] * Wd[(size_t)k*2048 + j];
  red[ko][jo] = s;
  __syncthreads();
  if (t < 16){
    float a = 0.f;
    #pragma unroll
    for (int q = 0; q < 16; ++q) a += red[q][t];
    hbuf[16*w + t] = a + bd[16*w + t];
  }
}

// ---------------- launch ----------------
extern "C" void kernel_launch(void* const* d_in, const int* in_sizes, int n_in,
                              void* d_out, int out_size, void* d_ws, size_t ws_size,
                              hipStream_t stream){
  (void)in_sizes; (void)n_in;
  const float* seq   = (const float*)d_in[0];
  const float* mask  = (const float*)d_in[1];
  const float* delta = (const float*)d_in[2];
  const float* dt    = (const float*)d_in[3];
  const float* h0    = (const float*)d_in[4];
  /* d_in[5] = dh0: carried dh never read by the reference cell */
  const float* prex0 = (const float*)d_in[6];
  const float* Wgx   = (const float*)d_in[7];
  const float* bgx   = (const float*)d_in[8];
  const float* Wgh   = (const float*)d_in[9];
  const float* bgh   = (const float*)d_in[10];
  const float* W     = (const float*)d_in[11];
  const float* U     = (const float*)d_in[12];
  const float* V     = (const float*)d_in[13];
  const float* b     = (const float*)d_in[14];
  const float* We    = (const float*)d_in[15];
  const float* be    = (const float*)d_in[16];
  const float* Wd    = (const float*)d_in[17];
  const float* bd    = (const float*)d_in[18];
  const float* Wo    = (const float*)d_in[19];
  const float* bo    = (const float*)d_in[20];

  float* wsf = (float*)d_ws;
  size_t wsFloats = ws_size / 4;
  size_t off = 0;
  int*   pubI   = (int*)(wsf + off);  off += 8192;       // 256 x 128B pub lines
  int*   ctrl   = (int*)(wsf + off);  off += 1024;       // arrival[c*4], done at 512+c*4
  float* meanv  = wsf + off;  off += 512;
  float* hbuf   = wsf + off;  off += 2048;
  float* zbuf   = wsf + off;  off += 2048;
  float* rhdbuf = wsf + off;  off += 2048;
  float* hpbuf  = wsf + off;  off += 2048;
  float* featbuf= wsf + off;  off += 256;
  float* Sp     = wsf + off;  off += (size_t)64*512;
  float* Cp     = wsf + off;  off += (size_t)64*512;
  float* Gh     = wsf + off;  off += (size_t)4096*2048;
  float* xh_all = wsf + off;  off += (size_t)NSTEP*512;
  float* HpDec  = wsf + off;  off += (size_t)4095*2048;
  size_t fixedF = off;

  // chunk area: overlays {Gx, scan temps} during precompute, PreTab chunk after
  float* area  = wsf + fixedF;
  float* Gx    = area;                                   // 4096*512
  float* segA  = area + (size_t)4096*512;                // 64*512
  float* segC  = segA + (size_t)64*512;
  float* segX0 = segC + (size_t)64*512;
  size_t preNeed = (size_t)4096*512 + (size_t)3*64*512;

  size_t areaF = (wsFloats > fixedF) ? (wsFloats - fixedF) : 0;
  long chunkSteps = (long)(areaF / 6144);
  if (areaF < preNeed || chunkSteps < 64){
    fillK<<<dim3(256), dim3(256), 0, stream>>>((float*)d_out, out_size,
                                               1.0e6f + (float)(ws_size >> 20));
    return;
  }
  if (chunkSteps > NSTEP) chunkSteps = NSTEP;
  int nch  = (int)((NSTEP + chunkSteps - 1) / chunkSteps);
  if (nch > 128) nch = 128;                        // ctrl capacity guard
  int clen = (NSTEP + nch - 1) / nch;

  // ---- precompute ----
  mean1K<<<dim3(64), dim3(512), 0, stream>>>(seq, mask, Sp, Cp);
  mean2K<<<dim3(1),  dim3(512), 0, stream>>>(Sp, Cp, meanv);
  gemmK<<<dim3(4, 32),  dim3(256), 0, stream>>>(delta, Wgx, Gx, 4096, 512, 512, bgx, 1, 0, 0, 0);
  gemmK<<<dim3(16, 32), dim3(256), 0, stream>>>(delta, Wgh, Gh, 4096, 2048, 512, bgh, 1, 0, 0, 0);
  scanSegK<<<dim3(64), dim3(512), 0, stream>>>(Gx, mask, seq, meanv, segA, segC);
  scanFixK<<<dim3(1),  dim3(512), 0, stream>>>(segA, segC, prex0, segX0);
  scanEmitK<<<dim3(64), dim3(512), 0, stream>>>(Gx, mask, seq, meanv, segX0, xh_all);
  initK<<<dim3(1), dim3(256), 0, stream>>>(pubI, ctrl, h0, hbuf);

  // ---- chunked recurrence: GEMMs -> persistent attempt -> fallback chain ----
  int chunkIdx = 0;
  for (int c0 = 0; c0 < NSTEP; c0 += clen, ++chunkIdx){
    int len = (c0 + clen <= NSTEP) ? clen : (NSTEP - c0);
    int gy  = (len + 127) / 128;
    gemmK<<<dim3(48, gy), dim3(256), 0, stream>>>(xh_all + (size_t)c0*512, W, area,
                                                  len, 6144, 512, b, 0, 0, 0, 0);
    gemmK<<<dim3(48, gy), dim3(256), 0, stream>>>(mask, V, area,
                                                  len, 6144, 512, nullptr, 0, 1, 1, c0);

    int* arrival = ctrl + 4*chunkIdx;
    int* done    = ctrl + 512 + 4*chunkIdx;
    if (chunkIdx > 0)
      syncStateK<<<dim3(1), dim3(256), 0, stream>>>(pubI, hbuf, ctrl + 512 + 4*(chunkIdx-1));

    rnnPersK<<<dim3(256), dim3(256), 0, stream>>>(U, area, c0, len, Gh, dt,
                                                  We, be, Wd, bd,
                                                  pubI, hpbuf, featbuf, HpDec,
                                                  arrival, done);

    for (int sl = 0; sl < len; ++sl){
      int g = c0 + sl;
      if (g == 4096){
        mlp1K<<<dim3(16),  dim3(256), 0, stream>>>(done, hpbuf, We, be, featbuf);
        mlp2K<<<dim3(128), dim3(256), 0, stream>>>(done, featbuf, Wd, bd, hbuf);
      }
      int src = (g < 4096) ? g : (8190 - g);
      const float* prow  = area + (size_t)sl*6144;
      const float* ghrow = Gh + (size_t)src*2048;
      float* hpd = (g >= 4096) ? (HpDec + (size_t)(8190 - g)*2048) : nullptr;
      stepAK<<<dim3(128), dim3(512), 0, stream>>>(done, U, prow, ghrow, hbuf, zbuf, rhdbuf);
      stepBK<<<dim3(64),  dim3(512), 0, stream>>>(done, U, prow + 4096, ghrow, dt + src,
                                                  zbuf, rhdbuf, hbuf, hpbuf, hpd);
    }
  }

  // out = HpDec @ Wo + bo : 4095x512, K=2048 (HpDec stored pre-reversed)
  gemmK<<<dim3(4, 32), dim3(256), 0, stream>>>(HpDec, Wo, (float*)d_out,
                                               4095, 512, 2048, bo, 0, 0, 0, 0);
}